// Round 7
// baseline (117.030 us; speedup 1.0000x reference)
//
#include <hip/hip_runtime.h>
#include <hip/hip_fp16.h>

#define HDIM 256
#define LDIM 384
#define BDIM 2
#define ADIM 14
#define HBS 20   // LDS hu-row stride (dwords): 80 B = 16B-aligned b128, <=2-way banks

typedef __attribute__((ext_vector_type(8))) _Float16 f16x8;
typedef __attribute__((ext_vector_type(2))) _Float16 f16x2;
typedef __attribute__((ext_vector_type(4))) float f32x4;

static __device__ __forceinline__ unsigned pack_f16(float x, float y) {
    f16x2 t = {(_Float16)x, (_Float16)y};     // x -> low 16
    union { f16x2 v; unsigned u; } c; c.v = t;
    return c.u;
}

// relu(a+b) on packed f16 pairs -> v_pk_add_f16 + v_pk_max_f16
static __device__ __forceinline__ unsigned relu_add(unsigned a, unsigned b) {
    union { unsigned u; f16x2 v; } ua, ub, ur;
    ua.u = a; ub.u = b;
    const f16x2 z = {(_Float16)0.f, (_Float16)0.f};
    ur.v = __builtin_elementwise_max(ua.v + ub.v, z);
    return ur.u;
}

// ---------------------------------------------------------------------------
// Kernel 1: LDS-tiled VALU GEMM (proven R2 structure, coalesced loads).
// C(768x512) = h @ [Wx; Ux]^T + bias, f16-packed outputs:
//   cols 0..255   -> hwP[row][c/2]                 (row-major f16 pairs)
//   cols 256..511 -> huK[b][kc][i][d]  kc=ch/32, d=(ch%32)/2  (kc-major!)
// ---------------------------------------------------------------------------
__global__ __launch_bounds__(256) void k_front(
    const float* __restrict__ h,
    const float* __restrict__ Wx_w, const float* __restrict__ Wx_b,
    const float* __restrict__ Ux_w, const float* __restrict__ Ux_b,
    unsigned* __restrict__ hwP, unsigned* __restrict__ huK)
{
    __shared__ float hsT[32][34];   // [kk][row], stride 34
    __shared__ float wsT[32][34];   // [kk][col]
    const int t  = threadIdx.x;
    const int tx = t & 15, ty = t >> 4;
    const int row0 = blockIdx.y * 32;    // 24 tiles over 768 rows
    const int col0 = blockIdx.x * 32;    // 16 tiles over 512 cols

    const int lr = t & 31;
    const int lk = (t >> 5) * 4;
    const float* __restrict__ hrow = &h[(row0 + lr) * HDIM];
    const int c_l = col0 + lr;
    const float* __restrict__ wrow = (c_l < HDIM) ? &Wx_w[c_l * HDIM]
                                                  : &Ux_w[(c_l - HDIM) * HDIM];

    float a00 = 0.f, a01 = 0.f, a10 = 0.f, a11 = 0.f;

    for (int k0 = 0; k0 < HDIM; k0 += 32) {
        const float4 hv = *(const float4*)&hrow[k0 + lk];
        const float4 wv = *(const float4*)&wrow[k0 + lk];
        hsT[lk + 0][lr] = hv.x; hsT[lk + 1][lr] = hv.y;
        hsT[lk + 2][lr] = hv.z; hsT[lk + 3][lr] = hv.w;
        wsT[lk + 0][lr] = wv.x; wsT[lk + 1][lr] = wv.y;
        wsT[lk + 2][lr] = wv.z; wsT[lk + 3][lr] = wv.w;
        __syncthreads();
        #pragma unroll
        for (int kk = 0; kk < 32; ++kk) {
            const float2 av = *(const float2*)&hsT[kk][ty * 2];
            const float2 bv = *(const float2*)&wsT[kk][tx * 2];
            a00 = fmaf(av.x, bv.x, a00); a01 = fmaf(av.x, bv.y, a01);
            a10 = fmaf(av.y, bv.x, a10); a11 = fmaf(av.y, bv.y, a11);
        }
        __syncthreads();
    }

    const int row = row0 + ty * 2;            // even; row,row+1 same b
    const int b = row / LDIM, i0 = row % LDIM;
    const int c0 = col0 + tx * 2;
    if (c0 < HDIM) {
        const float b0 = Wx_b[c0], b1 = Wx_b[c0 + 1];
        hwP[row * 128 + (c0 >> 1)]       = pack_f16(a00 + b0, a01 + b1);
        hwP[(row + 1) * 128 + (c0 >> 1)] = pack_f16(a10 + b0, a11 + b1);
    } else {
        const int ch = c0 - HDIM;             // even, 0..254
        const int kc = ch >> 5, d = (ch & 31) >> 1;   // d = tx (coalesced)
        const float b0 = Ux_b[ch], b1 = Ux_b[ch + 1];
        unsigned* __restrict__ dst = &huK[((b * 8 + kc) * LDIM) * 16 + d];
        dst[i0 * 16]       = pack_f16(a00 + b0, a01 + b1);
        dst[(i0 + 1) * 16] = pack_f16(a10 + b0, a11 + b1);
    }
}

// ---------------------------------------------------------------------------
// Kernel 2: one block (384 thr) per (b, i-pair).
// Per kc (K-chunk of 32): stage huK[b][kc] (24 KB, contiguous) -> LDS with
// coalesced float4s (register-prefetched one kc ahead), then A-frags via
// ds_read_b128 (pad-stride 20 dwords). B-frags from L1-hot Tx_w (fp32->pk).
// hw rows are wave-uniform uint4 loads. Dual-i MFMA. Epilogue as R6 (global X).
// ---------------------------------------------------------------------------
__global__ __launch_bounds__(384) void k_main(
    const unsigned* __restrict__ hwP, const unsigned* __restrict__ huK,
    const float* __restrict__ Tx_w, const float* __restrict__ Tx_b,
    const float* __restrict__ X, const int* __restrict__ mask,
    float* __restrict__ out)
{
    __shared__ unsigned hbuf[LDIM * HBS];   // 30.7 KB staged hu k-chunk
    __shared__ float m_lds[LDIM];
    __shared__ float part2[2][24 * 16 * 4]; // [i][group][a][{s2x,s2y,s2z,s1}]
    __shared__ float part_m[24];

    const int i0 = blockIdx.x * 2, i1 = i0 + 1;
    const int b  = blockIdx.y;
    const int tid = threadIdx.x;
    const int w = tid >> 6, lane = tid & 63;
    const int n = lane & 15, quad = lane >> 4;

    m_lds[tid] = (float)mask[b * LDIM + tid];

    const unsigned* __restrict__ hwr0 = &hwP[(b * LDIM + i0) * 128];
    const unsigned* __restrict__ hwr1 = &hwP[(b * LDIM + i1) * 128];
    const unsigned* __restrict__ srcb = &huK[(b * 8) * LDIM * 16];
    const int nn = (n < ADIM) ? n : 0;      // clamp: keep Tx_w reads in-bounds

    f32x4 acc0[4], acc1[4];
    #pragma unroll
    for (int t = 0; t < 4; ++t) {
        acc0[t] = (f32x4){0.f, 0.f, 0.f, 0.f};
        acc1[t] = (f32x4){0.f, 0.f, 0.f, 0.f};
    }

    // prefetch kc=0 into registers (coalesced: lane-contiguous 16B)
    uint4 pf[4];
    #pragma unroll
    for (int it = 0; it < 4; ++it)
        pf[it] = *(const uint4*)&srcb[it * 1536 + tid * 4];

    for (int kc = 0; kc < 8; ++kc) {
        if (kc) __syncthreads();            // prior chunk's reads done
        #pragma unroll
        for (int it = 0; it < 4; ++it) {
            const int flat = it * 1536 + tid * 4;
            const int jj = flat >> 4, dd = flat & 15;
            *(uint4*)&hbuf[jj * HBS + dd] = pf[it];
        }
        __syncthreads();
        if (kc < 7) {                       // prefetch next chunk under compute
            #pragma unroll
            for (int it = 0; it < 4; ++it)
                pf[it] = *(const uint4*)&srcb[(kc + 1) * 6144 + it * 1536 + tid * 4];
        }

        // B-frag from global Tx_w (14 KB, L1-hot): row nn, k = kc*32+quad*8..+7
        const float4 t0 = *(const float4*)&Tx_w[nn * HDIM + kc * 32 + quad * 8];
        const float4 t1 = *(const float4*)&Tx_w[nn * HDIM + kc * 32 + quad * 8 + 4];
        union { unsigned u[4]; f16x8 v; } bfrag;
        bfrag.u[0] = pack_f16(t0.x, t0.y); bfrag.u[1] = pack_f16(t0.z, t0.w);
        bfrag.u[2] = pack_f16(t1.x, t1.y); bfrag.u[3] = pack_f16(t1.z, t1.w);

        const int ko = kc * 16 + quad * 4;
        const uint4 hwa = *(const uint4*)&hwr0[ko];   // wave-uniform rows
        const uint4 hwb = *(const uint4*)&hwr1[ko];

        #pragma unroll
        for (int t = 0; t < 4; ++t) {
            const int jrow = (w * 4 + t) * 16 + n;
            const uint4 hu4 = *(const uint4*)&hbuf[jrow * HBS + quad * 4];  // ds_read_b128
            union { unsigned u[4]; f16x8 v; } af;
            af.u[0] = relu_add(hwa.x, hu4.x);
            af.u[1] = relu_add(hwa.y, hu4.y);
            af.u[2] = relu_add(hwa.z, hu4.z);
            af.u[3] = relu_add(hwa.w, hu4.w);
            acc0[t] = __builtin_amdgcn_mfma_f32_16x16x32_f16(af.v, bfrag.v, acc0[t], 0, 0, 0);
            af.u[0] = relu_add(hwb.x, hu4.x);
            af.u[1] = relu_add(hwb.y, hu4.y);
            af.u[2] = relu_add(hwb.z, hu4.z);
            af.u[3] = relu_add(hwb.w, hu4.w);
            acc1[t] = __builtin_amdgcn_mfma_f32_16x16x32_f16(af.v, bfrag.v, acc1[t], 0, 0, 0);
        }
    }

    // per-lane partials over this lane's 16 j's (a = n); D row = quad*4+r -> j
    float pm = 0.f;
    #pragma unroll
    for (int ii = 0; ii < 2; ++ii) {
        const f32x4* acc = ii ? acc1 : acc0;
        float s1 = 0.f, s2x = 0.f, s2y = 0.f, s2z = 0.f;
        if (n < ADIM) {
            const float txb = Tx_b[n];
            #pragma unroll
            for (int t = 0; t < 4; ++t) {
                #pragma unroll
                for (int r = 0; r < 4; ++r) {
                    const int jd = (w * 4 + t) * 16 + quad * 4 + r;
                    const float m = m_lds[jd];
                    const float g = acc[t][r] + txb;
                    const float mg = m * g;
                    const float* __restrict__ Xp = &X[((b * LDIM + jd) * ADIM + n) * 3];
                    s1 += mg;
                    s2x = fmaf(mg, Xp[0], s2x);
                    s2y = fmaf(mg, Xp[1], s2y);
                    s2z = fmaf(mg, Xp[2], s2z);
                    if (ii == 0) pm += m;
                }
            }
        }
        f32x4 sv = {s2x, s2y, s2z, s1};
        *(f32x4*)&part2[ii][((w * 4 + quad) * 16 + n) * 4] = sv;
    }
    if (n == 0) part_m[w * 4 + quad] = pm;
    __syncthreads();

    // finalize: threads 0..41 -> i0, threads 64..105 -> i1 (separate waves)
    int ii = -1, t42 = 0;
    if (tid < 42)                    { ii = 0; t42 = tid; }
    else if (tid >= 64 && tid < 106) { ii = 1; t42 = tid - 64; }
    if (ii >= 0) {
        const int a = t42 / 3, c = t42 % 3;
        const int i = ii ? i1 : i0;
        float S2 = 0.f, S1 = 0.f, msum = 0.f;
        #pragma unroll 4
        for (int g = 0; g < 24; ++g) {
            const float* __restrict__ p = &part2[ii][(g * 16 + a) * 4];
            S2 += p[c]; S1 += p[3]; msum += part_m[g];
        }
        const float denom = 1e-6f + msum;
        const int idx = ((b * LDIM + i) * ADIM + a) * 3 + c;
        const float xi = X[idx];
        float f = (xi * S1 - S2) / denom;
        f = fminf(fmaxf(f, -20.f), 20.f);
        out[idx] = xi + f;
    }
}

extern "C" void kernel_launch(void* const* d_in, const int* in_sizes, int n_in,
                              void* d_out, int out_size, void* d_ws, size_t ws_size,
                              hipStream_t stream) {
    (void)in_sizes; (void)n_in; (void)out_size; (void)ws_size;
    const float* h    = (const float*)d_in[0];
    const float* X    = (const float*)d_in[1];
    const int*   mask = (const int*)  d_in[2];
    const float* Wx_w = (const float*)d_in[3];
    const float* Wx_b = (const float*)d_in[4];
    const float* Ux_w = (const float*)d_in[5];
    const float* Ux_b = (const float*)d_in[6];
    const float* Tx_w = (const float*)d_in[7];
    const float* Tx_b = (const float*)d_in[8];
    float* out = (float*)d_out;

    unsigned* hwP = (unsigned*)d_ws;                   // [768][128] f16-pairs
    unsigned* huK = hwP + BDIM * LDIM * (HDIM / 2);    // [b][kc][384][16] f16-pairs

    k_front<<<dim3(16, 24), 256, 0, stream>>>(h, Wx_w, Wx_b, Ux_w, Ux_b, hwP, huK);
    k_main<<<dim3(LDIM / 2, BDIM), 384, 0, stream>>>(hwP, huK, Tx_w, Tx_b, X, mask, out);
}

// Round 8
// 100.543 us; speedup vs baseline: 1.1640x; 1.1640x over previous
//
#include <hip/hip_runtime.h>
#include <hip/hip_fp16.h>

#define HDIM 256
#define LDIM 384
#define BDIM 2
#define ADIM 14

typedef __attribute__((ext_vector_type(8))) _Float16 f16x8;
typedef __attribute__((ext_vector_type(2))) _Float16 f16x2;
typedef __attribute__((ext_vector_type(4))) float f32x4;

static __device__ __forceinline__ unsigned pack_f16(float x, float y) {
    f16x2 t = {(_Float16)x, (_Float16)y};     // x -> low 16
    union { f16x2 v; unsigned u; } c; c.v = t;
    return c.u;
}

// relu(a+b) on packed f16 pairs -> v_pk_add_f16 + v_pk_max_f16
static __device__ __forceinline__ unsigned relu_add(unsigned a, unsigned b) {
    union { unsigned u; f16x2 v; } ua, ub, ur;
    ua.u = a; ub.u = b;
    const f16x2 z = {(_Float16)0.f, (_Float16)0.f};
    ur.v = __builtin_elementwise_max(ua.v + ub.v, z);
    return ur.u;
}

// ---------------------------------------------------------------------------
// Kernel 1: LDS-free MFMA front GEMM (best-measured R3/R5 structure, no packer).
// One wave per 16x16 output tile of C(768 x 512) = h @ [Wx; Ux]^T + bias.
//   A = weight rows (channels), B = h rows (residues), K = 256 (8 chunks).
//   D: col=lane&15 -> residue-in-tile, row=quad*4+r -> channel.
// Output: hwP/huP[row][h2] packed f16 channel-pairs (row = b*L+i).
// ---------------------------------------------------------------------------
__global__ __launch_bounds__(256) void k_front(
    const float* __restrict__ h,
    const float* __restrict__ Wx_w, const float* __restrict__ Wx_b,
    const float* __restrict__ Ux_w, const float* __restrict__ Ux_b,
    unsigned* __restrict__ hwP, unsigned* __restrict__ huP)
{
    const int tid = threadIdx.x;
    const int w = tid >> 6, lane = tid & 63;
    const int n = lane & 15, quad = lane >> 4;
    const int g = blockIdx.x * 4 + w;           // 0..1535
    const int ctile = g & 31;                   // 0-15 Wx, 16-31 Ux
    const int rtile = g >> 5;                   // 48 row-tiles

    const int arow = (ctile & 15) * 16 + n;
    const float* __restrict__ Arow = (ctile < 16) ? &Wx_w[arow * HDIM]
                                                  : &Ux_w[arow * HDIM];
    const float* __restrict__ Brow = &h[(rtile * 16 + n) * HDIM];

    f32x4 acc = {0.f, 0.f, 0.f, 0.f};
    #pragma unroll
    for (int kc = 0; kc < 8; ++kc) {
        const int ko = kc * 32 + quad * 8;
        const float4 a0 = *(const float4*)&Arow[ko];
        const float4 a1 = *(const float4*)&Arow[ko + 4];
        const float4 b0 = *(const float4*)&Brow[ko];
        const float4 b1 = *(const float4*)&Brow[ko + 4];
        union { unsigned u[4]; f16x8 v; } af, bf;
        af.u[0] = pack_f16(a0.x, a0.y); af.u[1] = pack_f16(a0.z, a0.w);
        af.u[2] = pack_f16(a1.x, a1.y); af.u[3] = pack_f16(a1.z, a1.w);
        bf.u[0] = pack_f16(b0.x, b0.y); bf.u[1] = pack_f16(b0.z, b0.w);
        bf.u[2] = pack_f16(b1.x, b1.y); bf.u[3] = pack_f16(b1.z, b1.w);
        acc = __builtin_amdgcn_mfma_f32_16x16x32_f16(af.v, bf.v, acc, 0, 0, 0);
    }

    const int row = rtile * 16 + n;
    const int c0 = (ctile & 15) * 16 + quad * 4;
    const float4 bias = (ctile < 16) ? *(const float4*)&Wx_b[c0]
                                     : *(const float4*)&Ux_b[c0];
    uint2 pv;
    pv.x = pack_f16(acc[0] + bias.x, acc[1] + bias.y);
    pv.y = pack_f16(acc[2] + bias.z, acc[3] + bias.w);
    unsigned* __restrict__ dst = (ctile < 16) ? hwP : huP;
    *(uint2*)&dst[row * 128 + (ctile & 15) * 8 + quad * 2] = pv;
}

// ---------------------------------------------------------------------------
// Kernel 2: one block (384 thr) per (b, i-pair); hu4 load stream shared by
// both i's (halves L2 traffic). B-frags from L1-hot Tx_w directly (fp32->pk,
// proven R7). Global-X epilogue (R6 proved LDS staging neutral). LDS ~14 KB.
// ---------------------------------------------------------------------------
__global__ __launch_bounds__(384) void k_main(
    const unsigned* __restrict__ hwP, const unsigned* __restrict__ huP,
    const float* __restrict__ Tx_w, const float* __restrict__ Tx_b,
    const float* __restrict__ X, const int* __restrict__ mask,
    float* __restrict__ out)
{
    __shared__ float m_lds[LDIM];
    __shared__ float part2[2][24 * 16 * 4]; // [i][group][a][{s2x,s2y,s2z,s1}]
    __shared__ float part_m[24];

    const int i0 = blockIdx.x * 2, i1 = i0 + 1;
    const int b  = blockIdx.y;
    const int tid = threadIdx.x;
    const int w = tid >> 6, lane = tid & 63;
    const int n = lane & 15, quad = lane >> 4;

    m_lds[tid] = (float)mask[b * LDIM + tid];
    __syncthreads();

    const unsigned* __restrict__ hwr0 = &hwP[(b * LDIM + i0) * 128];
    const unsigned* __restrict__ hwr1 = &hwP[(b * LDIM + i1) * 128];
    const unsigned* __restrict__ hub  = &huP[b * LDIM * 128];
    const int nn = (n < ADIM) ? n : 0;      // clamp: keep Tx_w reads in-bounds

    f32x4 acc0[4], acc1[4];
    #pragma unroll
    for (int t = 0; t < 4; ++t) {
        acc0[t] = (f32x4){0.f, 0.f, 0.f, 0.f};
        acc1[t] = (f32x4){0.f, 0.f, 0.f, 0.f};
    }

    #pragma unroll 2
    for (int kc = 0; kc < 8; ++kc) {
        const int ko = kc * 16 + quad * 4;
        const uint4 hwa = *(const uint4*)&hwr0[ko];   // wave-uniform rows
        const uint4 hwb = *(const uint4*)&hwr1[ko];
        // B-frag from Tx_w (14 KB, L1-hot): row nn, k = kc*32+quad*8..+7
        const float4 t0 = *(const float4*)&Tx_w[nn * HDIM + kc * 32 + quad * 8];
        const float4 t1 = *(const float4*)&Tx_w[nn * HDIM + kc * 32 + quad * 8 + 4];
        union { unsigned u[4]; f16x8 v; } bfrag;
        bfrag.u[0] = pack_f16(t0.x, t0.y); bfrag.u[1] = pack_f16(t0.z, t0.w);
        bfrag.u[2] = pack_f16(t1.x, t1.y); bfrag.u[3] = pack_f16(t1.z, t1.w);
        #pragma unroll
        for (int t = 0; t < 4; ++t) {
            const int j = (w * 4 + t) * 16 + n;
            const uint4 hu4 = *(const uint4*)&hub[j * 128 + ko];   // shared by i0,i1
            union { unsigned u[4]; f16x8 v; } af;
            af.u[0] = relu_add(hwa.x, hu4.x);
            af.u[1] = relu_add(hwa.y, hu4.y);
            af.u[2] = relu_add(hwa.z, hu4.z);
            af.u[3] = relu_add(hwa.w, hu4.w);
            acc0[t] = __builtin_amdgcn_mfma_f32_16x16x32_f16(af.v, bfrag.v, acc0[t], 0, 0, 0);
            af.u[0] = relu_add(hwb.x, hu4.x);
            af.u[1] = relu_add(hwb.y, hu4.y);
            af.u[2] = relu_add(hwb.z, hu4.z);
            af.u[3] = relu_add(hwb.w, hu4.w);
            acc1[t] = __builtin_amdgcn_mfma_f32_16x16x32_f16(af.v, bfrag.v, acc1[t], 0, 0, 0);
        }
    }

    // per-lane partials over this lane's 16 j's (a = n); D row = quad*4+r -> j
    float pm = 0.f;
    #pragma unroll
    for (int ii = 0; ii < 2; ++ii) {
        const f32x4* acc = ii ? acc1 : acc0;
        float s1 = 0.f, s2x = 0.f, s2y = 0.f, s2z = 0.f;
        if (n < ADIM) {
            const float txb = Tx_b[n];
            #pragma unroll
            for (int t = 0; t < 4; ++t) {
                #pragma unroll
                for (int r = 0; r < 4; ++r) {
                    const int jd = (w * 4 + t) * 16 + quad * 4 + r;
                    const float m = m_lds[jd];
                    const float g = acc[t][r] + txb;
                    const float mg = m * g;
                    const float* __restrict__ Xp = &X[((b * LDIM + jd) * ADIM + n) * 3];
                    s1 += mg;
                    s2x = fmaf(mg, Xp[0], s2x);
                    s2y = fmaf(mg, Xp[1], s2y);
                    s2z = fmaf(mg, Xp[2], s2z);
                    if (ii == 0) pm += m;
                }
            }
        }
        f32x4 sv = {s2x, s2y, s2z, s1};
        *(f32x4*)&part2[ii][((w * 4 + quad) * 16 + n) * 4] = sv;
    }
    if (n == 0) part_m[w * 4 + quad] = pm;
    __syncthreads();

    // finalize: threads 0..41 -> i0, threads 64..105 -> i1 (separate waves)
    int ii = -1, t42 = 0;
    if (tid < 42)                    { ii = 0; t42 = tid; }
    else if (tid >= 64 && tid < 106) { ii = 1; t42 = tid - 64; }
    if (ii >= 0) {
        const int a = t42 / 3, c = t42 % 3;
        const int i = ii ? i1 : i0;
        float S2 = 0.f, S1 = 0.f, msum = 0.f;
        #pragma unroll 4
        for (int g = 0; g < 24; ++g) {
            const float* __restrict__ p = &part2[ii][(g * 16 + a) * 4];
            S2 += p[c]; S1 += p[3]; msum += part_m[g];
        }
        const float denom = 1e-6f + msum;
        const int idx = ((b * LDIM + i) * ADIM + a) * 3 + c;
        const float xi = X[idx];
        float f = (xi * S1 - S2) / denom;
        f = fminf(fmaxf(f, -20.f), 20.f);
        out[idx] = xi + f;
    }
}

extern "C" void kernel_launch(void* const* d_in, const int* in_sizes, int n_in,
                              void* d_out, int out_size, void* d_ws, size_t ws_size,
                              hipStream_t stream) {
    (void)in_sizes; (void)n_in; (void)out_size; (void)ws_size;
    const float* h    = (const float*)d_in[0];
    const float* X    = (const float*)d_in[1];
    const int*   mask = (const int*)  d_in[2];
    const float* Wx_w = (const float*)d_in[3];
    const float* Wx_b = (const float*)d_in[4];
    const float* Ux_w = (const float*)d_in[5];
    const float* Ux_b = (const float*)d_in[6];
    const float* Tx_w = (const float*)d_in[7];
    const float* Tx_b = (const float*)d_in[8];
    float* out = (float*)d_out;

    unsigned* hwP = (unsigned*)d_ws;                   // [768][128] f16-pairs
    unsigned* huP = hwP + BDIM * LDIM * (HDIM / 2);    // [768][128] f16-pairs

    k_front<<<384, 256, 0, stream>>>(h, Wx_w, Wx_b, Ux_w, Ux_b, hwP, huP);
    k_main<<<dim3(LDIM / 2, BDIM), 384, 0, stream>>>(hwP, huP, Tx_w, Tx_b, X, mask, out);
}